// Round 11
// baseline (269.462 us; speedup 1.0000x reference)
//
#include <hip/hip_runtime.h>
#include <hip/hip_bf16.h>
#include <math.h>
#include <stdint.h>

// ---------------------------------------------------------------------------
// MultiSimilarityLoss on MI355X.
//   x: [B=4096, D=1024] fp32 (L2-normalized rows), labels: [B] int32
//   out: scalar fp32 = mean of mined multi-similarity loss
// Pipeline (R11) -- 3 dispatches:
//   K1: cvt fp32->bf16, fused gmin/gmax/cnt init (block 0)  [= R10]
//   K2: sim = x @ x^T, square 1024-block grid, BK=32 pipelined dbuf,
//       T2 swizzle, direct write + row-side stats  [= R10, 79.5us, 432TF]
//   K3: rowloss, 4 rows/block: INLINE-ASM software-pipelined loads.
//       R6-R10 showed VGPR=24 -> compiler sinks each float4 load to its
//       use -> 1 load in flight -> latency-serialized (VALUBusy 7%).
//       asm global_load_dwordx4 cannot be sunk; tied "+v" operands on the
//       counted s_waitcnt order consumers after the wait (r282 lesson).
//       2-deep pipeline: issue chunk c+1's 4 loads, vmcnt(4), process c.
//       Accumulation order bitwise-identical to R10.
// ---------------------------------------------------------------------------

#define THRESH    0.5f
#define MARGIN    0.1f
#define SCALE_POS 2.0f
#define SCALE_NEG 40.0f
#define POS_CAP   (1.0f - 1e-5f)

typedef __bf16 bf16x8 __attribute__((ext_vector_type(8)));
typedef float  f32x4  __attribute__((ext_vector_type(4)));

__device__ __forceinline__ uint16_t f2bf(float f) {
  union { float f; uint32_t u; } v; v.f = f;
  uint32_t u = v.u;
  u += 0x7FFFu + ((u >> 16) & 1u);
  return (uint16_t)(u >> 16);
}

__device__ __forceinline__ uint32_t fenc(float f) {
  union { float f; uint32_t u; } v; v.f = f;
  return (v.u & 0x80000000u) ? ~v.u : (v.u ^ 0x80000000u);
}
__device__ __forceinline__ float fdec(uint32_t k) {
  union { float f; uint32_t u; } v;
  v.u = (k & 0x80000000u) ? (k ^ 0x80000000u) : ~k;
  return v.f;
}

// ---- K1: cvt + stat/counter init -------------------------------------------
__global__ __launch_bounds__(256) void cvt_bf16_kernel(
    const float* __restrict__ x, uint16_t* __restrict__ y, int n,
    uint32_t* __restrict__ gmin, uint32_t* __restrict__ gmax,
    uint32_t* __restrict__ cnt, int B) {
  const int tid = threadIdx.x;
  int i = (blockIdx.x * 256 + tid) * 4;
  if (i + 3 < n) {
    float4 v = *(const float4*)(x + i);
    ushort4 o;
    o.x = f2bf(v.x); o.y = f2bf(v.y); o.z = f2bf(v.z); o.w = f2bf(v.w);
    *(ushort4*)(y + i) = o;
  }
  if (blockIdx.x == 0) {
    for (int j = tid; j < B; j += 256) {
      gmin[j] = 0xFFFFFFFFu;
      gmax[j] = 0u;
    }
    if (tid == 0) *cnt = 0u;
  }
}

#if defined(__has_builtin)
#if __has_builtin(__builtin_amdgcn_global_load_lds)
#define HAVE_GLL 1
#endif
#endif

__device__ __forceinline__ void stage16(const uint16_t* g, uint16_t* lds_wave_base, int lane) {
#ifdef HAVE_GLL
  __builtin_amdgcn_global_load_lds(
      (const __attribute__((address_space(1))) void*)g,
      (__attribute__((address_space(3))) void*)lds_wave_base, 16, 0, 0);
#else
  *(uint4*)(lds_wave_base + lane * 8) = *(const uint4*)g;
#endif
}

// ---- K2: sim = X @ X^T, square grid (4 blocks/CU), BK=32 pipelined dbuf ----
// EXACT R10 kernel (79.5us, MfmaUtil 16.7%). Do not touch.
__global__ __launch_bounds__(256) void simgemm_kernel(
    const uint16_t* __restrict__ X, const int* __restrict__ labels,
    float* __restrict__ C, uint32_t* __restrict__ gmin, uint32_t* __restrict__ gmax,
    int B, int D) {
  __shared__ __align__(16) uint16_t sT[2][2][128 * 32];
  __shared__ int slabR[128];
  __shared__ int slabC[128];

  const int nblk = B >> 7;            // 32
  const int nb   = nblk * nblk;       // 1024

  int t = blockIdx.x;
  { const int cpx = nb >> 3; t = (t & 7) * cpx + (t >> 3); }
  const int bi = t / nblk;
  const int bj = t - bi * nblk;
  const int bm = bi * 128;
  const int bn = bj * 128;

  const int tid  = threadIdx.x;
  const int wave = tid >> 6;
  const int lane = tid & 63;
  const int waveM = wave >> 1, waveN = wave & 1;

  if (tid < 128) slabR[tid] = labels[bm + tid];
  else           slabC[tid - 128] = labels[bn + tid - 128];

  const uint16_t* gA = X + (size_t)bm * D;
  const uint16_t* gB = X + (size_t)bn * D;

  int srcOff[2];
#pragma unroll
  for (int s = 0; s < 2; ++s) {
    const int idx = s * 256 + tid;
    const int row = idx >> 2;
    const int cb  = ((idx & 3) << 4) ^ ((row & 3) << 4);
    srcOff[s] = row * D + (cb >> 1);
  }

  const int fr = lane & 15;
  const int fq = lane >> 4;
  const int sw = (fr & 3) << 4;

  f32x4 acc[4][4] = {};

  const int NT = D >> 5;

#pragma unroll
  for (int s = 0; s < 2; ++s) {
    uint16_t* dA = &sT[0][0][0] + (s * 256 + wave * 64) * 8;
    uint16_t* dB = &sT[0][1][0] + (s * 256 + wave * 64) * 8;
    stage16(gA + srcOff[s], dA, lane);
    stage16(gB + srcOff[s], dB, lane);
  }
  __syncthreads();

  int cur = 0;
  for (int kt = 0; kt < NT; ++kt) {
    if (kt + 1 < NT) {
      const int k0 = (kt + 1) << 5;
#pragma unroll
      for (int s = 0; s < 2; ++s) {
        uint16_t* dA = &sT[cur ^ 1][0][0] + (s * 256 + wave * 64) * 8;
        uint16_t* dB = &sT[cur ^ 1][1][0] + (s * 256 + wave * 64) * 8;
        stage16(gA + srcOff[s] + k0, dA, lane);
        stage16(gB + srcOff[s] + k0, dB, lane);
      }
    }

    const char* tA = (const char*)&sT[cur][0][0];
    const char* tB = (const char*)&sT[cur][1][0];
    const int cbyte = (fq * 16) ^ sw;
    bf16x8 af[4], bfv[4];
#pragma unroll
    for (int mt = 0; mt < 4; ++mt) {
      const int rowa = waveM * 64 + mt * 16 + fr;
      af[mt] = *(const bf16x8*)(tA + rowa * 64 + cbyte);
    }
#pragma unroll
    for (int nt = 0; nt < 4; ++nt) {
      const int rowb = waveN * 64 + nt * 16 + fr;
      bfv[nt] = *(const bf16x8*)(tB + rowb * 64 + cbyte);
    }
#pragma unroll
    for (int mt = 0; mt < 4; ++mt)
#pragma unroll
      for (int nt = 0; nt < 4; ++nt)
        acc[mt][nt] = __builtin_amdgcn_mfma_f32_16x16x32_bf16(
            af[mt], bfv[nt], acc[mt][nt], 0, 0, 0);

    __syncthreads();
    cur ^= 1;
  }

#pragma unroll
  for (int mt = 0; mt < 4; ++mt) {
#pragma unroll
    for (int nt = 0; nt < 4; ++nt) {
      const int col = bn + waveN * 64 + nt * 16 + fr;
#pragma unroll
      for (int r = 0; r < 4; ++r) {
        const int row = bm + waveM * 64 + mt * 16 + fq * 4 + r;
        C[(size_t)row * B + col] = acc[mt][nt][r];
      }
    }
  }

  const float INF = __builtin_inff();

  int lr[4][4];
#pragma unroll
  for (int mt = 0; mt < 4; ++mt)
#pragma unroll
    for (int r = 0; r < 4; ++r)
      lr[mt][r] = slabR[waveM * 64 + mt * 16 + fq * 4 + r];
  int lc[4];
#pragma unroll
  for (int nt = 0; nt < 4; ++nt) lc[nt] = slabC[waveN * 64 + nt * 16 + fr];

  float rmin[4][4], rmax[4][4];
#pragma unroll
  for (int mt = 0; mt < 4; ++mt)
#pragma unroll
    for (int r = 0; r < 4; ++r) { rmin[mt][r] = INF; rmax[mt][r] = -INF; }

#pragma unroll
  for (int mt = 0; mt < 4; ++mt) {
#pragma unroll
    for (int nt = 0; nt < 4; ++nt) {
      const int gcol = bn + waveN * 64 + nt * 16 + fr;
#pragma unroll
      for (int r = 0; r < 4; ++r) {
        const int grow = bm + waveM * 64 + mt * 16 + fq * 4 + r;
        const float s = acc[mt][nt][r];
        if (lr[mt][r] == lc[nt]) {
          if (grow != gcol && s < POS_CAP) rmin[mt][r] = fminf(rmin[mt][r], s);
        } else {
          rmax[mt][r] = fmaxf(rmax[mt][r], s);
        }
      }
    }
  }
#pragma unroll
  for (int mt = 0; mt < 4; ++mt)
#pragma unroll
    for (int r = 0; r < 4; ++r) {
#pragma unroll
      for (int m = 1; m < 16; m <<= 1) {
        rmin[mt][r] = fminf(rmin[mt][r], __shfl_xor(rmin[mt][r], m, 64));
        rmax[mt][r] = fmaxf(rmax[mt][r], __shfl_xor(rmax[mt][r], m, 64));
      }
    }
  if (fr == 0) {
#pragma unroll
    for (int mt = 0; mt < 4; ++mt)
#pragma unroll
      for (int r = 0; r < 4; ++r) {
        const int grow = bm + waveM * 64 + mt * 16 + fq * 4 + r;
        if (rmin[mt][r] < INF)  atomicMin(&gmin[grow], fenc(rmin[mt][r]));
        if (rmax[mt][r] > -INF) atomicMax(&gmax[grow], fenc(rmax[mt][r]));
      }
  }
}

// ---- K3: rowloss, asm-pipelined loads (8 in flight), fused final reduce ----
#define GL16(dst, p) \
  asm volatile("global_load_dwordx4 %0, %1, off" : "=v"(dst) : "v"(p))
#define WAIT4(nstr, a, b, c, d) \
  asm volatile("s_waitcnt vmcnt(" nstr ")" : "+v"(a), "+v"(b), "+v"(c), "+v"(d))

__device__ __forceinline__ void proc4r(
    const f32x4 v, const int4 lb, int jbase, int i, int li,
    float minpos, float maxneg, float& ps, float& ns) {
  const float s4[4] = {v[0], v[1], v[2], v[3]};
  const int   l4[4] = {lb.x, lb.y, lb.z, lb.w};
#pragma unroll
  for (int q = 0; q < 4; ++q) {
    const int jj = jbase + q;
    const float s = s4[q];
    if (l4[q] == li) {
      if (jj != i && s < POS_CAP && (s - MARGIN < maxneg))
        ps += __expf(-SCALE_POS * (s - THRESH));
    } else {
      if (s + MARGIN > minpos)
        ns += __expf(SCALE_NEG * (s - THRESH));
    }
  }
}

__global__ __launch_bounds__(256) void rowloss_kernel(
    const float* __restrict__ sim, const int* __restrict__ labels,
    const uint32_t* __restrict__ gmin, const uint32_t* __restrict__ gmax,
    float* __restrict__ rowbuf, float* __restrict__ out,
    uint32_t* __restrict__ cnt, int B) {
  __shared__ int   slab[4096];
  __shared__ float red[4][8];
  __shared__ float fred[4];
  __shared__ int   isLast;

  const int tid  = threadIdx.x;
  const int wave = tid >> 6;
  const int lane = tid & 63;
  const float INF = __builtin_inff();

  for (int tq = tid; tq < (B >> 2); tq += 256)
    ((int4*)slab)[tq] = ((const int4*)labels)[tq];
  __syncthreads();

  const int i0 = blockIdx.x * 4;

  float minpos[4], maxneg[4];
  bool  haspos[4], hasneg[4];
  int   li[4];
#pragma unroll
  for (int r = 0; r < 4; ++r) {
    const uint32_t km = gmin[i0 + r], kx = gmax[i0 + r];
    haspos[r] = (km != 0xFFFFFFFFu);
    hasneg[r] = (kx != 0u);
    minpos[r] = haspos[r] ? fdec(km) : INF;
    maxneg[r] = hasneg[r] ? fdec(kx) : -INF;
    li[r] = slab[i0 + r];
  }

  float ps[4] = {}, ns[4] = {};

  if (B == 4096) {
    // 4 chunks of 1024 cols; 2-deep asm pipeline, 8 loads in flight.
    const float* p0 = sim + (size_t)i0 * B + tid * 4;
    const float* p1 = p0 + B;
    const float* p2 = p0 + 2 * B;
    const float* p3 = p0 + 3 * B;
    const int j0 = tid * 4;

    f32x4 a0, a1, a2, a3, b0, b1, b2, b3;
    GL16(a0, p0);        GL16(a1, p1);        GL16(a2, p2);        GL16(a3, p3);
    GL16(b0, p0 + 1024); GL16(b1, p1 + 1024); GL16(b2, p2 + 1024); GL16(b3, p3 + 1024);

    WAIT4("4", a0, a1, a2, a3);          // chunk 0 landed; chunk 1 in flight
    {
      const int4 lb = *(const int4*)(&slab[j0]);
      proc4r(a0, lb, j0, i0,     li[0], minpos[0], maxneg[0], ps[0], ns[0]);
      proc4r(a1, lb, j0, i0 + 1, li[1], minpos[1], maxneg[1], ps[1], ns[1]);
      proc4r(a2, lb, j0, i0 + 2, li[2], minpos[2], maxneg[2], ps[2], ns[2]);
      proc4r(a3, lb, j0, i0 + 3, li[3], minpos[3], maxneg[3], ps[3], ns[3]);
    }
    GL16(a0, p0 + 2048); GL16(a1, p1 + 2048); GL16(a2, p2 + 2048); GL16(a3, p3 + 2048);

    WAIT4("4", b0, b1, b2, b3);
    {
      const int j = j0 + 1024;
      const int4 lb = *(const int4*)(&slab[j]);
      proc4r(b0, lb, j, i0,     li[0], minpos[0], maxneg[0], ps[0], ns[0]);
      proc4r(b1, lb, j, i0 + 1, li[1], minpos[1], maxneg[1], ps[1], ns[1]);
      proc4r(b2, lb, j, i0 + 2, li[2], minpos[2], maxneg[2], ps[2], ns[2]);
      proc4r(b3, lb, j, i0 + 3, li[3], minpos[3], maxneg[3], ps[3], ns[3]);
    }
    GL16(b0, p0 + 3072); GL16(b1, p1 + 3072); GL16(b2, p2 + 3072); GL16(b3, p3 + 3072);

    WAIT4("4", a0, a1, a2, a3);
    {
      const int j = j0 + 2048;
      const int4 lb = *(const int4*)(&slab[j]);
      proc4r(a0, lb, j, i0,     li[0], minpos[0], maxneg[0], ps[0], ns[0]);
      proc4r(a1, lb, j, i0 + 1, li[1], minpos[1], maxneg[1], ps[1], ns[1]);
      proc4r(a2, lb, j, i0 + 2, li[2], minpos[2], maxneg[2], ps[2], ns[2]);
      proc4r(a3, lb, j, i0 + 3, li[3], minpos[3], maxneg[3], ps[3], ns[3]);
    }

    WAIT4("0", b0, b1, b2, b3);
    {
      const int j = j0 + 3072;
      const int4 lb = *(const int4*)(&slab[j]);
      proc4r(b0, lb, j, i0,     li[0], minpos[0], maxneg[0], ps[0], ns[0]);
      proc4r(b1, lb, j, i0 + 1, li[1], minpos[1], maxneg[1], ps[1], ns[1]);
      proc4r(b2, lb, j, i0 + 2, li[2], minpos[2], maxneg[2], ps[2], ns[2]);
      proc4r(b3, lb, j, i0 + 3, li[3], minpos[3], maxneg[3], ps[3], ns[3]);
    }
  } else {
    // generic fallback (same math, same per-thread order)
    const int iters = B >> 10;
    for (int it = 0; it < iters; ++it) {
      const int j = it * 1024 + tid * 4;
      const int4 lb = *(const int4*)(&slab[j]);
#pragma unroll
      for (int r = 0; r < 4; ++r) {
        const f32x4 v = *(const f32x4*)(sim + (size_t)(i0 + r) * B + j);
        proc4r(v, lb, j, i0 + r, li[r], minpos[r], maxneg[r], ps[r], ns[r]);
      }
    }
  }

#pragma unroll
  for (int r = 0; r < 4; ++r) {
#pragma unroll
    for (int m = 32; m > 0; m >>= 1) {
      ps[r] += __shfl_xor(ps[r], m, 64);
      ns[r] += __shfl_xor(ns[r], m, 64);
    }
  }
  if (lane == 0) {
#pragma unroll
    for (int r = 0; r < 4; ++r) { red[wave][r] = ps[r]; red[wave][4 + r] = ns[r]; }
  }
  __syncthreads();

  if (tid < 4) {
    const int r = tid;
    const float P = red[0][r] + red[1][r] + red[2][r] + red[3][r];
    const float N = red[0][4 + r] + red[1][4 + r] + red[2][4 + r] + red[3][4 + r];
    const bool has_row = haspos[r] && hasneg[r] && (P > 0.f) && (N > 0.f);
    rowbuf[i0 + r] = has_row
        ? (log1pf(P) * (1.0f / SCALE_POS) + log1pf(N) * (1.0f / SCALE_NEG))
        : 0.f;
  }
  __threadfence();
  __syncthreads();

  if (tid == 0) {
    const uint32_t v = atomicAdd(cnt, 1u);
    isLast = (v == (uint32_t)(gridDim.x - 1)) ? 1 : 0;
  }
  __syncthreads();

  if (isLast) {
    __threadfence();
    float s = 0.f;
    for (int j = tid * 4; j < B; j += 1024) {
      float4 v = *(const float4*)(rowbuf + j);
      s += v.x + v.y + v.z + v.w;
    }
#pragma unroll
    for (int m = 32; m > 0; m >>= 1) s += __shfl_xor(s, m, 64);
    if (lane == 0) fred[wave] = s;
    __syncthreads();
    if (tid == 0)
      out[0] = (fred[0] + fred[1] + fred[2] + fred[3]) * (1.0f / (float)B);
  }
}

// ---------------------------------------------------------------------------
extern "C" void kernel_launch(void* const* d_in, const int* in_sizes, int n_in,
                              void* d_out, int out_size, void* d_ws, size_t ws_size,
                              hipStream_t stream) {
  const float* x      = (const float*)d_in[0];
  const int*   labels = (const int*)d_in[1];
  float*       out    = (float*)d_out;

  const int B = in_sizes[1];           // 4096
  const int D = in_sizes[0] / B;       // 1024

  char* ws = (char*)d_ws;
  uint16_t* xbf = (uint16_t*)ws;       ws += (((size_t)B * D * 2) + 255) & ~(size_t)255;
  float* sim = (float*)ws;             ws += (size_t)B * B * 4;
  uint32_t* gmin = (uint32_t*)ws;      ws += (size_t)B * 4;
  uint32_t* gmax = (uint32_t*)ws;      ws += (size_t)B * 4;
  float* rowbuf = (float*)ws;          ws += (size_t)B * 4;
  uint32_t* cnt = (uint32_t*)ws;       ws += 256;

  const int n = B * D;
  cvt_bf16_kernel<<<n / 1024, 256, 0, stream>>>(x, xbf, n, gmin, gmax, cnt, B);

  const int nblk = B / 128;
  const int nb   = nblk * nblk;        // 1024 square tiles = 4 blocks/CU
  simgemm_kernel<<<nb, 256, 0, stream>>>(xbf, labels, sim, gmin, gmax, B, D);

  rowloss_kernel<<<B / 4, 256, 0, stream>>>(sim, labels, gmin, gmax,
                                            rowbuf, out, cnt, B);
}